// Round 6
// baseline (148.721 us; speedup 1.0000x reference)
//
#include <hip/hip_runtime.h>

#define T_STEPS 256
#define B_SZ 128
#define I_SZ 1024
#define O_SZ 512

typedef short bf16x8 __attribute__((ext_vector_type(8)));
typedef float f32x16 __attribute__((ext_vector_type(16)));

#define PLANE (O_SZ * I_SZ)                 // ushorts per split plane
#define WS_NEEDED ((size_t)3 * PLANE * 2)   // 3 MB

// ---------------------------------------------------------------------------
// helpers
// ---------------------------------------------------------------------------
__device__ __forceinline__ ushort f2bf_rne(float f) {
    uint u = __float_as_uint(f);
    u += ((u >> 16) & 1u) + 0x7fffu;        // round-to-nearest-even
    return (ushort)(u >> 16);
}
__device__ __forceinline__ uint pk2(float lo, float hi) {
    // exact for x in {0,1}: truncation == RNE
    return (__float_as_uint(lo) >> 16) | (__float_as_uint(hi) & 0xffff0000u);
}
__device__ __forceinline__ void gload_lds16(const void* g, void* l) {
    typedef const void __attribute__((address_space(1))) gvt;
    typedef void __attribute__((address_space(3))) svt;
    __builtin_amdgcn_global_load_lds((gvt*)g, (svt*)l, 16, 0, 0);
}

// ---------------------------------------------------------------------------
// W split: W[n][k] fp32 -> 3 bf16 planes in MFMA-fragment order (BK=32 tiles):
//   plane[p] layout [kt(32)][nsg(16)][k16(2)][lane(64)][8]
//   element (n,k): kt=k>>5, k16=(k>>4)&1, kh=(k>>3)&1, l=(n&31)|(kh<<5),
//   j=k&7, nsg=n>>5
// ---------------------------------------------------------------------------
__global__ __launch_bounds__(256) void wsplit_kernel(
    const float* __restrict__ W, ushort* __restrict__ wsp)
{
    const int t = blockIdx.x * 256 + threadIdx.x;   // 65536 threads
    const int n = t >> 7, kq = t & 127, k0 = kq * 8;
    const float* wp = W + (size_t)n * I_SZ + k0;

    uint q1[4], q2[4], q3[4];
#pragma unroll
    for (int jj = 0; jj < 4; ++jj) {
        ushort s1[2], s2[2], s3[2];
#pragma unroll
        for (int e = 0; e < 2; ++e) {
            float w0 = wp[jj * 2 + e];
            ushort a1 = f2bf_rne(w0);
            float  f1 = __uint_as_float((uint)a1 << 16);
            float  r1 = w0 - f1;
            ushort a2 = f2bf_rne(r1);
            float  f2 = __uint_as_float((uint)a2 << 16);
            float  r2 = r1 - f2;
            ushort a3 = f2bf_rne(r2);
            s1[e] = a1; s2[e] = a2; s3[e] = a3;
        }
        q1[jj] = (uint)s1[0] | ((uint)s1[1] << 16);
        q2[jj] = (uint)s2[0] | ((uint)s2[1] << 16);
        q3[jj] = (uint)s3[0] | ((uint)s3[1] << 16);
    }
    const int kt = k0 >> 5, k16 = (k0 >> 4) & 1, kh = (k0 >> 3) & 1;
    const int l = (n & 31) | (kh << 5), nsg = n >> 5;
    const size_t off = ((((size_t)kt * 16 + nsg) * 2 + k16) * 64 + l) * 8;
    *(uint4*)(wsp + off)             = make_uint4(q1[0], q1[1], q1[2], q1[3]);
    *(uint4*)(wsp + PLANE + off)     = make_uint4(q2[0], q2[1], q2[2], q2[3]);
    *(uint4*)(wsp + 2 * PLANE + off) = make_uint4(q3[0], q3[1], q3[2], q3[3]);
}

// ---------------------------------------------------------------------------
// MFMA GEMM, phase-template schedule (T3+T4+T5):
//   256x256 tile, 8 waves 2m x 4n (per-wave 128x64), BK=32, 32 K-steps,
//   3 phases/step (one per split plane), 16 MFMA per phase.
//   Per-wave issue order per step: A(4 glob) P0(2 glds) P1(2) P2(2)
//   -> derived waits: P0 vmcnt(4), P1 vmcnt(8), P2 vmcnt(8), A-write vmcnt(4).
//   Never drains vmcnt to 0 inside the loop.
// ---------------------------------------------------------------------------
__global__ __launch_bounds__(512, 2) void gemm_mfma5(
    const float* __restrict__ X, const ushort* __restrict__ wsp,
    const float* __restrict__ bias, float* __restrict__ S)
{
    __shared__ uint lds[32768];   // 2 bufs x (A 4096 uints | B 12288 uints)

    const int tid  = threadIdx.x;
    const int lane = tid & 63;
    const int w    = tid >> 6;          // 0..7
    const int wm   = w >> 2, wn = w & 3;

    // bijective XCD swizzle: 256 wgs = 8 XCDs x 32; nb-pairs of same mb adjacent
    const int bid     = blockIdx.x;
    const int logical = (bid & 7) * 32 + (bid >> 3);
    const int mb = logical >> 1, nb = logical & 1;
    const int row0 = mb * 256;

    // ---- A staging: thread t -> row r = t>>1, k-half h = t&1 (16 floats)
    const int ar = tid >> 1, ah = tid & 1;
    const float* pa = X + (size_t)(row0 + ar) * I_SZ + ah * 16;
    // frag dest: [msub(8)][k16(2)][lane(64)][8 ushorts]; kh=0 slot and kh=1 slot
    const uint aw0 = (((uint)(ar >> 5) * 2 + ah) * 64 + (ar & 31)) * 4;

    // ---- B staging: wave w stages nsg_local = w, both k16, all 3 planes
    uint bsrc[3][2];
#pragma unroll
    for (int p = 0; p < 3; ++p)
#pragma unroll
        for (int q = 0; q < 2; ++q)
            bsrc[p][q] = (uint)p * PLANE + (uint)(((nb * 8 + w) * 2 + q) * 512) + lane * 8;

    f32x16 acc[4][2];
#pragma unroll
    for (int i = 0; i < 4; ++i)
#pragma unroll
        for (int j = 0; j < 2; ++j)
#pragma unroll
            for (int r = 0; r < 16; ++r) acc[i][j][r] = 0.f;

#define READ_B(BC, P) do {                                                    \
    _Pragma("unroll")                                                         \
    for (int sn_ = 0; sn_ < 2; ++sn_)                                         \
        _Pragma("unroll")                                                     \
        for (int k_ = 0; k_ < 2; ++k_)                                        \
            bf[sn_][k_] = *(const bf16x8*)((BC) + ((P) * 16 +                 \
                (wn * 2 + sn_) * 2 + k_) * 256 + lane * 4);                   \
} while (0)

#define MFMA16() do {                                                         \
    __builtin_amdgcn_s_setprio(1);                                            \
    _Pragma("unroll")                                                         \
    for (int k_ = 0; k_ < 2; ++k_)                                            \
        _Pragma("unroll")                                                     \
        for (int m_ = 0; m_ < 4; ++m_)                                        \
            _Pragma("unroll")                                                 \
            for (int sn_ = 0; sn_ < 2; ++sn_)                                 \
                acc[m_][sn_] = __builtin_amdgcn_mfma_f32_32x32x16_bf16(       \
                    af[m_][k_], bf[sn_][k_], acc[m_][sn_], 0, 0, 0);          \
    __builtin_amdgcn_s_setprio(0);                                            \
} while (0)

    // ---- prologue: stage step 0 into buf0, drain, write A, barrier
    {
#pragma unroll
        for (int p = 0; p < 3; ++p) {
            gload_lds16(wsp + bsrc[p][0], lds + 4096 + (p * 16 + w * 2 + 0) * 256);
            gload_lds16(wsp + bsrc[p][1], lds + 4096 + (p * 16 + w * 2 + 1) * 256);
        }
        float4 g0 = *(const float4*)(pa);
        float4 g1 = *(const float4*)(pa + 4);
        float4 g2 = *(const float4*)(pa + 8);
        float4 g3 = *(const float4*)(pa + 12);
        asm volatile("s_waitcnt vmcnt(0)" ::: "memory");
        *(uint4*)(lds + aw0)       = make_uint4(pk2(g0.x, g0.y), pk2(g0.z, g0.w),
                                                pk2(g1.x, g1.y), pk2(g1.z, g1.w));
        *(uint4*)(lds + aw0 + 128) = make_uint4(pk2(g2.x, g2.y), pk2(g2.z, g2.w),
                                                pk2(g3.x, g3.y), pk2(g3.z, g3.w));
        asm volatile("s_waitcnt lgkmcnt(0)" ::: "memory");
        __builtin_amdgcn_s_barrier();
        __builtin_amdgcn_sched_barrier(0);
    }

    bf16x8 af[4][2], bf[2][2];

    for (int kt = 0; kt < 31; ++kt) {
        const uint* Ac = lds + (kt & 1) * 16384;
        const uint* Bc = Ac + 4096;
        uint* An = lds + ((kt & 1) ^ 1) * 16384;
        uint* Bn = An + 4096;
        const uint kadd = (uint)(kt + 1) * 16384;

        // ---------------- phase 0 (plane 0)
        asm volatile("s_waitcnt vmcnt(4)" ::: "memory");   // prev A+P0 landed
        __builtin_amdgcn_sched_barrier(0);
#pragma unroll
        for (int m = 0; m < 4; ++m)
#pragma unroll
            for (int k16 = 0; k16 < 2; ++k16)
                af[m][k16] = *(const bf16x8*)(Ac + ((wm * 4 + m) * 2 + k16) * 256 + lane * 4);
        READ_B(Bc, 0);
        const float* pk = pa + (kt + 1) * 32;
        float4 g0 = *(const float4*)(pk);
        float4 g1 = *(const float4*)(pk + 4);
        float4 g2 = *(const float4*)(pk + 8);
        float4 g3 = *(const float4*)(pk + 12);
        gload_lds16(wsp + bsrc[0][0] + kadd, Bn + (w * 2 + 0) * 256);
        gload_lds16(wsp + bsrc[0][1] + kadd, Bn + (w * 2 + 1) * 256);
        __builtin_amdgcn_s_barrier();
        asm volatile("s_waitcnt lgkmcnt(0)" ::: "memory");
        __builtin_amdgcn_sched_barrier(0);
        MFMA16();
        __builtin_amdgcn_s_barrier();

        // ---------------- phase 1 (plane 1)
        asm volatile("s_waitcnt vmcnt(8)" ::: "memory");   // prev P1 landed
        __builtin_amdgcn_sched_barrier(0);
        READ_B(Bc, 1);
        gload_lds16(wsp + bsrc[1][0] + kadd, Bn + (16 + w * 2 + 0) * 256);
        gload_lds16(wsp + bsrc[1][1] + kadd, Bn + (16 + w * 2 + 1) * 256);
        __builtin_amdgcn_s_barrier();
        asm volatile("s_waitcnt lgkmcnt(0)" ::: "memory");
        __builtin_amdgcn_sched_barrier(0);
        MFMA16();
        __builtin_amdgcn_s_barrier();

        // ---------------- phase 2 (plane 2)
        asm volatile("s_waitcnt vmcnt(8)" ::: "memory");   // prev P2 landed
        __builtin_amdgcn_sched_barrier(0);
        READ_B(Bc, 2);
        asm volatile("s_waitcnt vmcnt(4)" ::: "memory");   // this step's A regs ready
        __builtin_amdgcn_sched_barrier(0);
        *(uint4*)(An + aw0)       = make_uint4(pk2(g0.x, g0.y), pk2(g0.z, g0.w),
                                               pk2(g1.x, g1.y), pk2(g1.z, g1.w));
        *(uint4*)(An + aw0 + 128) = make_uint4(pk2(g2.x, g2.y), pk2(g2.z, g2.w),
                                               pk2(g3.x, g3.y), pk2(g3.z, g3.w));
        gload_lds16(wsp + bsrc[2][0] + kadd, Bn + (32 + w * 2 + 0) * 256);
        gload_lds16(wsp + bsrc[2][1] + kadd, Bn + (32 + w * 2 + 1) * 256);
        asm volatile("s_waitcnt lgkmcnt(0)" ::: "memory"); // pin A write above barrier
        __builtin_amdgcn_s_barrier();
        __builtin_amdgcn_sched_barrier(0);
        MFMA16();
        __builtin_amdgcn_s_barrier();
    }

    // ---- peeled last step (kt = 31, buffer parity 1, no staging)
    {
        const uint* Ac = lds + 16384;
        const uint* Bc = Ac + 4096;
        asm volatile("s_waitcnt vmcnt(4)" ::: "memory");
        __builtin_amdgcn_sched_barrier(0);
#pragma unroll
        for (int m = 0; m < 4; ++m)
#pragma unroll
            for (int k16 = 0; k16 < 2; ++k16)
                af[m][k16] = *(const bf16x8*)(Ac + ((wm * 4 + m) * 2 + k16) * 256 + lane * 4);
        READ_B(Bc, 0);
        MFMA16();
        asm volatile("s_waitcnt vmcnt(2)" ::: "memory");
        __builtin_amdgcn_sched_barrier(0);
        READ_B(Bc, 1);
        MFMA16();
        asm volatile("s_waitcnt vmcnt(0)" ::: "memory");
        __builtin_amdgcn_sched_barrier(0);
        READ_B(Bc, 2);
        MFMA16();
    }

    // epilogue: D row=(reg&3)+8*(reg>>2)+4*(lane>>5), col=lane&31 (B operand)
    const int rowbase = row0 + wm * 128 + 4 * (lane >> 5);
#pragma unroll
    for (int sn = 0; sn < 2; ++sn) {
        const int colb = nb * 256 + (wn * 2 + sn) * 32 + (lane & 31);
        const float bv = bias[colb];
#pragma unroll
        for (int m = 0; m < 4; ++m)
#pragma unroll
            for (int r = 0; r < 16; ++r) {
                const int rr = rowbase + m * 32 + (r & 3) + 8 * (r >> 2);
                S[(size_t)rr * O_SZ + colb] = acc[m][sn][r] + bv;
            }
    }
#undef READ_B
#undef MFMA16
}

// ---------------------------------------------------------------------------
// Fallback fp32 GEMM if ws too small for split planes.
// ---------------------------------------------------------------------------
#define BM 128
#define BN 128
#define BKF 32
#define LDT 132

__global__ __launch_bounds__(256, 2) void gemm_fp32(
    const float* __restrict__ X, const float* __restrict__ W,
    const float* __restrict__ bias, float* __restrict__ S)
{
    __shared__ float As[BKF][LDT];
    __shared__ float Ws[BKF][LDT];
    const int tid = threadIdx.x;
    const int nb = blockIdx.x & 3;
    const int mb = blockIdx.x >> 2;
    const int tx = (tid & 7) | ((tid & 128) >> 4);
    const int ty = (tid >> 3) & 15;
    const float* Ablk = X + (size_t)mb * BM * I_SZ;
    const float* Wblk = W + (size_t)nb * BN * I_SZ;
    const int skq = tid & 7;
    const int srow = tid >> 3;
    float acc[8][8];
#pragma unroll
    for (int i = 0; i < 8; ++i)
#pragma unroll
        for (int j = 0; j < 8; ++j) acc[i][j] = 0.f;
    for (int kt = 0; kt < I_SZ; kt += BKF) {
#pragma unroll
        for (int it = 0; it < 4; ++it) {
            const int row = srow + it * 32;
            float4 a = *(const float4*)(Ablk + (size_t)row * I_SZ + kt + skq * 4);
            As[skq * 4 + 0][row] = a.x; As[skq * 4 + 1][row] = a.y;
            As[skq * 4 + 2][row] = a.z; As[skq * 4 + 3][row] = a.w;
            float4 wv = *(const float4*)(Wblk + (size_t)row * I_SZ + kt + skq * 4);
            Ws[skq * 4 + 0][row] = wv.x; Ws[skq * 4 + 1][row] = wv.y;
            Ws[skq * 4 + 2][row] = wv.z; Ws[skq * 4 + 3][row] = wv.w;
        }
        __syncthreads();
#pragma unroll
        for (int kk = 0; kk < BKF; ++kk) {
            float4 a0 = *(const float4*)&As[kk][ty * 8];
            float4 a1 = *(const float4*)&As[kk][ty * 8 + 4];
            float4 w0 = *(const float4*)&Ws[kk][tx * 8];
            float4 w1 = *(const float4*)&Ws[kk][tx * 8 + 4];
            float av[8] = {a0.x, a0.y, a0.z, a0.w, a1.x, a1.y, a1.z, a1.w};
            float wv[8] = {w0.x, w0.y, w0.z, w0.w, w1.x, w1.y, w1.z, w1.w};
#pragma unroll
            for (int i = 0; i < 8; ++i)
#pragma unroll
                for (int j = 0; j < 8; ++j) acc[i][j] += av[i] * wv[j];
        }
        __syncthreads();
    }
    const int row0 = mb * BM + ty * 8;
    const int col0 = nb * BN + tx * 8;
    float bv[8];
#pragma unroll
    for (int j = 0; j < 8; ++j) bv[j] = bias[col0 + j];
#pragma unroll
    for (int i = 0; i < 8; ++i) {
        float4 o0 = {acc[i][0] + bv[0], acc[i][1] + bv[1], acc[i][2] + bv[2], acc[i][3] + bv[3]};
        float4 o1 = {acc[i][4] + bv[4], acc[i][5] + bv[5], acc[i][6] + bv[6], acc[i][7] + bv[7]};
        *(float4*)(S + (size_t)(row0 + i) * O_SZ + col0)     = o0;
        *(float4*)(S + (size_t)(row0 + i) * O_SZ + col0 + 4) = o1;
    }
}

// ---------------------------------------------------------------------------
// Fused scan + tpre. Blocks 0..255: per-(b,o) temporal scan (burst prefetch).
// Blocks 256..767: times_pre backward search. Co-resident for latency hiding.
// ---------------------------------------------------------------------------
__global__ __launch_bounds__(256) void scan_tpre_kernel(
    float* __restrict__ out, const float* __restrict__ wl_arr,
    const float* __restrict__ x)
{
    const int bid = blockIdx.x;
    if (bid < 256) {
#pragma clang fp contract(off)
        const int gid = bid * 256 + threadIdx.x;   // b*O + o
        const float wl = wl_arr[gid & (O_SZ - 1)];
        const float decay_s = 0.8f;
        const float decay_m = 0.9f;

        float cur[8], nxt[8];
#pragma unroll
        for (int i = 0; i < 8; ++i) cur[i] = out[(size_t)i * (B_SZ * O_SZ) + gid];

        float ep = 0.f, u = 0.f, osp = 0.f, vref = 0.f, tpost = -1.f;
        for (int tb = 0; tb < T_STEPS; tb += 8) {
            if (tb < T_STEPS - 8) {
#pragma unroll
                for (int i = 0; i < 8; ++i)
                    nxt[i] = out[(size_t)(tb + 8 + i) * (B_SZ * O_SZ) + gid];
            }
#pragma unroll
            for (int i = 0; i < 8; ++i) {
                const int t = tb + i;
                const size_t idx = (size_t)t * (B_SZ * O_SZ) + gid;
                float iresp = cur[i] + osp * wl;
                ep = ep * decay_s + iresp;
                u  = u * decay_m + ep / 5.0f;
                if (vref > 0.f) u = 0.f;
                osp = (u > 1.0f) ? 1.f : 0.f;
                float v = 2.0f * osp + (vref - 1.0f);
                vref = v < 0.f ? 0.f : (v > 2.f ? 2.f : v);
                float cand = osp * ((float)t + 1.0f) - 1.0f;
                tpost = cand > tpost ? cand : tpost;
                out[idx] = osp;
            }
#pragma unroll
            for (int i = 0; i < 8; ++i) cur[i] = nxt[i];
        }
        out[(size_t)T_STEPS * B_SZ * O_SZ + (size_t)B_SZ * I_SZ + gid] = tpost;
    } else {
        const int gid = (bid - 256) * 256 + threadIdx.x;   // b*I + i
        float tp = -1.f;
        for (int t = T_STEPS - 1; t >= 0; --t) {
            if (x[(size_t)t * (B_SZ * I_SZ) + gid] > 0.5f) { tp = (float)t; break; }
        }
        out[(size_t)T_STEPS * B_SZ * O_SZ + gid] = tp;
    }
}

// ---------------------------------------------------------------------------
extern "C" void kernel_launch(void* const* d_in, const int* in_sizes, int n_in,
                              void* d_out, int out_size, void* d_ws, size_t ws_size,
                              hipStream_t stream) {
    const float* x    = (const float*)d_in[0];
    const float* w    = (const float*)d_in[1];
    const float* bias = (const float*)d_in[2];
    const float* wl   = (const float*)d_in[3];
    float* out = (float*)d_out;

    if (ws_size >= WS_NEEDED) {
        ushort* wsp = (ushort*)d_ws;
        wsplit_kernel<<<dim3(256), dim3(256), 0, stream>>>(w, wsp);
        gemm_mfma5<<<dim3(256), dim3(512), 0, stream>>>(x, wsp, bias, out);
    } else {
        gemm_fp32<<<dim3(1024), dim3(256), 0, stream>>>(x, w, bias, out);
    }
    scan_tpre_kernel<<<dim3(768), dim3(256), 0, stream>>>(out, wl, x);
}

// Round 7
// 130.141 us; speedup vs baseline: 1.1428x; 1.1428x over previous
//
#include <hip/hip_runtime.h>

#define T_STEPS 256
#define B_SZ 128
#define I_SZ 1024
#define O_SZ 512

typedef short bf16x8 __attribute__((ext_vector_type(8)));
typedef float f32x16 __attribute__((ext_vector_type(16)));

#define PLANE (O_SZ * I_SZ)                 // ushorts per split plane
#define WS_NEEDED ((size_t)3 * PLANE * 2)   // 3 MB

// ---------------------------------------------------------------------------
// helpers
// ---------------------------------------------------------------------------
__device__ __forceinline__ ushort f2bf_rne(float f) {
    uint u = __float_as_uint(f);
    u += ((u >> 16) & 1u) + 0x7fffu;        // round-to-nearest-even
    return (ushort)(u >> 16);
}
__device__ __forceinline__ uint pk2(float lo, float hi) {
    // exact for x in {0,1}: truncation == RNE
    return (__float_as_uint(lo) >> 16) | (__float_as_uint(hi) & 0xffff0000u);
}
__device__ __forceinline__ void gload_lds16(const void* g, void* l) {
    typedef const void __attribute__((address_space(1))) gvt;
    typedef void __attribute__((address_space(3))) svt;
    __builtin_amdgcn_global_load_lds((gvt*)g, (svt*)l, 16, 0, 0);
}

// ---------------------------------------------------------------------------
// W split: W[n][k] fp32 -> 3 bf16 planes in MFMA-fragment order (BK=32):
//   plane[p] layout [kt(32)][nsg(16)][k16(2)][lane(64)][8]
//   element (n,k): kt=k>>5, k16=(k>>4)&1, kh=(k>>3)&1, l=(n&31)|(kh<<5),
//   j=k&7, nsg=n>>5
// ---------------------------------------------------------------------------
__global__ __launch_bounds__(256) void wsplit_kernel(
    const float* __restrict__ W, ushort* __restrict__ wsp)
{
    const int t = blockIdx.x * 256 + threadIdx.x;   // 65536 threads
    const int n = t >> 7, kq = t & 127, k0 = kq * 8;
    const float* wp = W + (size_t)n * I_SZ + k0;

    uint q1[4], q2[4], q3[4];
#pragma unroll
    for (int jj = 0; jj < 4; ++jj) {
        ushort s1[2], s2[2], s3[2];
#pragma unroll
        for (int e = 0; e < 2; ++e) {
            float w0 = wp[jj * 2 + e];
            ushort a1 = f2bf_rne(w0);
            float  f1 = __uint_as_float((uint)a1 << 16);
            float  r1 = w0 - f1;
            ushort a2 = f2bf_rne(r1);
            float  f2 = __uint_as_float((uint)a2 << 16);
            float  r2 = r1 - f2;
            ushort a3 = f2bf_rne(r2);
            s1[e] = a1; s2[e] = a2; s3[e] = a3;
        }
        q1[jj] = (uint)s1[0] | ((uint)s1[1] << 16);
        q2[jj] = (uint)s2[0] | ((uint)s2[1] << 16);
        q3[jj] = (uint)s3[0] | ((uint)s3[1] << 16);
    }
    const int kt = k0 >> 5, k16 = (k0 >> 4) & 1, kh = (k0 >> 3) & 1;
    const int l = (n & 31) | (kh << 5), nsg = n >> 5;
    const size_t off = ((((size_t)kt * 16 + nsg) * 2 + k16) * 64 + l) * 8;
    *(uint4*)(wsp + off)             = make_uint4(q1[0], q1[1], q1[2], q1[3]);
    *(uint4*)(wsp + PLANE + off)     = make_uint4(q2[0], q2[1], q2[2], q2[3]);
    *(uint4*)(wsp + 2 * PLANE + off) = make_uint4(q3[0], q3[1], q3[2], q3[3]);
}

// ---------------------------------------------------------------------------
// MFMA GEMM: S[M][O] = X[M][K](binary) @ (W1+W2+W3)^T + bias
//   256x256 tile, 8 waves (4m x 2n), per-wave 64x128, BK=32,
//   double-buffered LDS (128KB, 1 block/CU), single barrier per K-step,
//   dist-1 prefetch, compiler-scheduled (measured best: 114 us, 903 TF).
// ---------------------------------------------------------------------------
__global__ __launch_bounds__(512, 2) void gemm_mfma2(
    const float* __restrict__ X, const ushort* __restrict__ wsp,
    const float* __restrict__ bias, float* __restrict__ S)
{
    __shared__ uint lds_u[32768];   // 2 bufs x (A 4096 uints | B 12288 uints)

    const int tid  = threadIdx.x;
    const int lane = tid & 63;
    const int w    = tid >> 6;          // 0..7
    const int wm   = w >> 1, wn = w & 1;

    // bijective XCD swizzle: 256 wgs = 8 XCDs x 32; nb-pairs of same mb adjacent
    const int bid     = blockIdx.x;
    const int logical = (bid & 7) * 32 + (bid >> 3);
    const int mb = logical >> 1, nb = logical & 1;
    const int row0 = mb * 256;

    // ---- A staging: thread owns fragment-lanes f0=2*tid, f0+1 (rows m0, m0+1)
    const int f0   = tid * 2;
    const int msub = f0 >> 7, k16s = (f0 >> 6) & 1, l0 = f0 & 63;
    const int m0   = msub * 32 + (l0 & 31);
    const int ks   = (l0 >> 5) * 8;
    const float* pa = X + (size_t)(row0 + m0) * I_SZ + k16s * 16 + ks;
    const int aoff = f0 * 4;            // uint offset within A region

    // ---- B staging: 48 x 1KB chunks per K-step; wave w issues chunks 6w..6w+5
    uint bsrc[6];
    const int c0 = w * 6;
#pragma unroll
    for (int i = 0; i < 6; ++i) {
        const int c = c0 + i, p = c >> 4, r = c & 15;
        const int nsgl = r >> 1, k16 = r & 1;
        bsrc[i] = (uint)p * PLANE + (uint)(((nb * 8 + nsgl) * 2 + k16) * 512) + lane * 8;
    }

    f32x16 acc[2][4];
#pragma unroll
    for (int i = 0; i < 2; ++i)
#pragma unroll
        for (int j = 0; j < 4; ++j)
#pragma unroll
            for (int r = 0; r < 16; ++r) acc[i][j][r] = 0.f;

    // ---- prologue: stage kt=0 into buf0
    {
        float4 a0 = *(const float4*)pa;
        float4 a1 = *(const float4*)(pa + 4);
        float4 a2 = *(const float4*)(pa + I_SZ);
        float4 a3 = *(const float4*)(pa + I_SZ + 4);
#pragma unroll
        for (int i = 0; i < 6; ++i)
            gload_lds16(wsp + bsrc[i], lds_u + 4096 + (c0 + i) * 256);
        uint* ad = lds_u + aoff;
        *(uint4*)ad       = make_uint4(pk2(a0.x, a0.y), pk2(a0.z, a0.w),
                                       pk2(a1.x, a1.y), pk2(a1.z, a1.w));
        *(uint4*)(ad + 4) = make_uint4(pk2(a2.x, a2.y), pk2(a2.z, a2.w),
                                       pk2(a3.x, a3.y), pk2(a3.z, a3.w));
        __syncthreads();
    }

    for (int kt = 0; kt < 32; ++kt) {
        const int cur = kt & 1;
        const uint* Au = lds_u + cur * 16384;
        const uint* Bu = Au + 4096;
        uint* nbase = lds_u + (cur ^ 1) * 16384;

        // stage kt+1: issue loads BEFORE the MFMA cluster
        float4 a0, a1, a2, a3;
        const bool pref = (kt < 31);
        if (pref) {
            const float* p0 = pa + (kt + 1) * 32;
            a0 = *(const float4*)p0;
            a1 = *(const float4*)(p0 + 4);
            a2 = *(const float4*)(p0 + I_SZ);
            a3 = *(const float4*)(p0 + I_SZ + 4);
            const uint kadd = (uint)(kt + 1) * 16384;
#pragma unroll
            for (int i = 0; i < 6; ++i)
                gload_lds16(wsp + bsrc[i] + kadd, nbase + 4096 + (c0 + i) * 256);
        }

        // compute current buffer: 48 MFMA
#pragma unroll
        for (int k16 = 0; k16 < 2; ++k16) {
            bf16x8 af0 = *(const bf16x8*)(Au + (wm * 4 + k16) * 256 + lane * 4);
            bf16x8 af1 = *(const bf16x8*)(Au + (wm * 4 + 2 + k16) * 256 + lane * 4);
#pragma unroll
            for (int p = 0; p < 3; ++p)
#pragma unroll
                for (int sn = 0; sn < 4; ++sn) {
                    const int c = (p * 8 + wn * 4 + sn) * 2 + k16;
                    bf16x8 bf = *(const bf16x8*)(Bu + c * 256 + lane * 4);
                    acc[0][sn] = __builtin_amdgcn_mfma_f32_32x32x16_bf16(af0, bf, acc[0][sn], 0, 0, 0);
                    acc[1][sn] = __builtin_amdgcn_mfma_f32_32x32x16_bf16(af1, bf, acc[1][sn], 0, 0, 0);
                }
        }

        // late A write into next buffer (loads have drained under the MFMAs)
        if (pref) {
            uint* ad = nbase + aoff;
            *(uint4*)ad       = make_uint4(pk2(a0.x, a0.y), pk2(a0.z, a0.w),
                                           pk2(a1.x, a1.y), pk2(a1.z, a1.w));
            *(uint4*)(ad + 4) = make_uint4(pk2(a2.x, a2.y), pk2(a2.z, a2.w),
                                           pk2(a3.x, a3.y), pk2(a3.z, a3.w));
        }
        __syncthreads();
    }

    // epilogue: D row=(reg&3)+8*(reg>>2)+4*(lane>>5), col=lane&31 (from B operand)
    const int colb = nb * 256 + wn * 128 + (lane & 31);
    const int rowb = row0 + wm * 64 + 4 * (lane >> 5);
    float bv[4];
#pragma unroll
    for (int sn = 0; sn < 4; ++sn) bv[sn] = bias[colb + sn * 32];
#pragma unroll
    for (int sm = 0; sm < 2; ++sm)
#pragma unroll
        for (int sn = 0; sn < 4; ++sn)
#pragma unroll
            for (int r = 0; r < 16; ++r) {
                const int rr = rowb + sm * 32 + (r & 3) + 8 * (r >> 2);
                S[(size_t)rr * O_SZ + colb + sn * 32] = acc[sm][sn][r] + bv[sn];
            }
}

// ---------------------------------------------------------------------------
// Fallback fp32 GEMM if ws too small for split planes.
// ---------------------------------------------------------------------------
#define BM 128
#define BN 128
#define BKF 32
#define LDT 132

__global__ __launch_bounds__(256, 2) void gemm_fp32(
    const float* __restrict__ X, const float* __restrict__ W,
    const float* __restrict__ bias, float* __restrict__ S)
{
    __shared__ float As[BKF][LDT];
    __shared__ float Ws[BKF][LDT];
    const int tid = threadIdx.x;
    const int nb = blockIdx.x & 3;
    const int mb = blockIdx.x >> 2;
    const int tx = (tid & 7) | ((tid & 128) >> 4);
    const int ty = (tid >> 3) & 15;
    const float* Ablk = X + (size_t)mb * BM * I_SZ;
    const float* Wblk = W + (size_t)nb * BN * I_SZ;
    const int skq = tid & 7;
    const int srow = tid >> 3;
    float acc[8][8];
#pragma unroll
    for (int i = 0; i < 8; ++i)
#pragma unroll
        for (int j = 0; j < 8; ++j) acc[i][j] = 0.f;
    for (int kt = 0; kt < I_SZ; kt += BKF) {
#pragma unroll
        for (int it = 0; it < 4; ++it) {
            const int row = srow + it * 32;
            float4 a = *(const float4*)(Ablk + (size_t)row * I_SZ + kt + skq * 4);
            As[skq * 4 + 0][row] = a.x; As[skq * 4 + 1][row] = a.y;
            As[skq * 4 + 2][row] = a.z; As[skq * 4 + 3][row] = a.w;
            float4 wv = *(const float4*)(Wblk + (size_t)row * I_SZ + kt + skq * 4);
            Ws[skq * 4 + 0][row] = wv.x; Ws[skq * 4 + 1][row] = wv.y;
            Ws[skq * 4 + 2][row] = wv.z; Ws[skq * 4 + 3][row] = wv.w;
        }
        __syncthreads();
#pragma unroll
        for (int kk = 0; kk < BKF; ++kk) {
            float4 a0 = *(const float4*)&As[kk][ty * 8];
            float4 a1 = *(const float4*)&As[kk][ty * 8 + 4];
            float4 w0 = *(const float4*)&Ws[kk][tx * 8];
            float4 w1 = *(const float4*)&Ws[kk][tx * 8 + 4];
            float av[8] = {a0.x, a0.y, a0.z, a0.w, a1.x, a1.y, a1.z, a1.w};
            float wv[8] = {w0.x, w0.y, w0.z, w0.w, w1.x, w1.y, w1.z, w1.w};
#pragma unroll
            for (int i = 0; i < 8; ++i)
#pragma unroll
                for (int j = 0; j < 8; ++j) acc[i][j] += av[i] * wv[j];
        }
        __syncthreads();
    }
    const int row0 = mb * BM + ty * 8;
    const int col0 = nb * BN + tx * 8;
    float bv[8];
#pragma unroll
    for (int j = 0; j < 8; ++j) bv[j] = bias[col0 + j];
#pragma unroll
    for (int i = 0; i < 8; ++i) {
        float4 o0 = {acc[i][0] + bv[0], acc[i][1] + bv[1], acc[i][2] + bv[2], acc[i][3] + bv[3]};
        float4 o1 = {acc[i][4] + bv[4], acc[i][5] + bv[5], acc[i][6] + bv[6], acc[i][7] + bv[7]};
        *(float4*)(S + (size_t)(row0 + i) * O_SZ + col0)     = o0;
        *(float4*)(S + (size_t)(row0 + i) * O_SZ + col0 + 4) = o1;
    }
}

// ---------------------------------------------------------------------------
// Fused scan + tpre. Blocks 0..255: per-(b,o) temporal scan (burst prefetch:
// load next 8 t-values BEFORE the serial compute block). Blocks 256..767:
// times_pre backward search. Co-residency: tpre waves hide scan load latency.
// ---------------------------------------------------------------------------
__global__ __launch_bounds__(256) void scan_tpre_kernel(
    float* __restrict__ out, const float* __restrict__ wl_arr,
    const float* __restrict__ x)
{
    const int bid = blockIdx.x;
    if (bid < 256) {
#pragma clang fp contract(off)
        const int gid = bid * 256 + threadIdx.x;   // b*O + o
        const float wl = wl_arr[gid & (O_SZ - 1)];
        const float decay_s = 0.8f;
        const float decay_m = 0.9f;

        float cur[8], nxt[8];
#pragma unroll
        for (int i = 0; i < 8; ++i) cur[i] = out[(size_t)i * (B_SZ * O_SZ) + gid];

        float ep = 0.f, u = 0.f, osp = 0.f, vref = 0.f, tpost = -1.f;
        for (int tb = 0; tb < T_STEPS; tb += 8) {
            if (tb < T_STEPS - 8) {
#pragma unroll
                for (int i = 0; i < 8; ++i)
                    nxt[i] = out[(size_t)(tb + 8 + i) * (B_SZ * O_SZ) + gid];
            }
#pragma unroll
            for (int i = 0; i < 8; ++i) {
                const int t = tb + i;
                const size_t idx = (size_t)t * (B_SZ * O_SZ) + gid;
                float iresp = cur[i] + osp * wl;
                ep = ep * decay_s + iresp;
                u  = u * decay_m + ep / 5.0f;
                if (vref > 0.f) u = 0.f;
                osp = (u > 1.0f) ? 1.f : 0.f;
                float v = 2.0f * osp + (vref - 1.0f);
                vref = v < 0.f ? 0.f : (v > 2.f ? 2.f : v);
                float cand = osp * ((float)t + 1.0f) - 1.0f;
                tpost = cand > tpost ? cand : tpost;
                out[idx] = osp;
            }
#pragma unroll
            for (int i = 0; i < 8; ++i) cur[i] = nxt[i];
        }
        out[(size_t)T_STEPS * B_SZ * O_SZ + (size_t)B_SZ * I_SZ + gid] = tpost;
    } else {
        const int gid = (bid - 256) * 256 + threadIdx.x;   // b*I + i
        float tp = -1.f;
        for (int t = T_STEPS - 1; t >= 0; --t) {
            if (x[(size_t)t * (B_SZ * I_SZ) + gid] > 0.5f) { tp = (float)t; break; }
        }
        out[(size_t)T_STEPS * B_SZ * O_SZ + gid] = tp;
    }
}

// ---------------------------------------------------------------------------
extern "C" void kernel_launch(void* const* d_in, const int* in_sizes, int n_in,
                              void* d_out, int out_size, void* d_ws, size_t ws_size,
                              hipStream_t stream) {
    const float* x    = (const float*)d_in[0];
    const float* w    = (const float*)d_in[1];
    const float* bias = (const float*)d_in[2];
    const float* wl   = (const float*)d_in[3];
    float* out = (float*)d_out;

    if (ws_size >= WS_NEEDED) {
        ushort* wsp = (ushort*)d_ws;
        wsplit_kernel<<<dim3(256), dim3(256), 0, stream>>>(w, wsp);
        gemm_mfma2<<<dim3(256), dim3(512), 0, stream>>>(x, wsp, bias, out);
    } else {
        gemm_fp32<<<dim3(1024), dim3(256), 0, stream>>>(x, w, bias, out);
    }
    scan_tpre_kernel<<<dim3(768), dim3(256), 0, stream>>>(out, wl, x);
}